// Round 1
// baseline (355.717 us; speedup 1.0000x reference)
//
#include <hip/hip_runtime.h>
#include <math.h>

// Problem constants
#define BE 128          // B * N_EVENTS
#define LW 4096         // LONG_WINDOW
#define LF 16           // LONG_FRAMES
#define LC 2049         // LONG_COEFFS
#define MM 2048         // LW/2 (complex FFT size)
#define NSAMP 32768     // N_SAMPLES
#define NB 8            // B
#define NEV 16          // N_EVENTS

// workspace layout in floats
#define OFF_ENERGY 0ull                      // BE*16*4096   = 8388608
#define OFF_TP     8388608ull                // BE*16*2049*2 = 8392704
#define OFF_ATOMS  16781312ull               // BE*32768     = 4194304
#define OFF_MAXP   20975616ull               // 1024

// ---------------- kernel 1: energy = env*(2*noise-1), transposed to (be,f,n)
__global__ __launch_bounds__(256) void k_energy(const float* __restrict__ env,
                                                const float* __restrict__ noise,
                                                float* __restrict__ ws) {
    __shared__ float tile[256][17];
    int be = blockIdx.x >> 4;
    int n0 = (blockIdx.x & 15) << 8;
    int tid = threadIdx.x;
    size_t base = (size_t)be * (LW * LF) + (size_t)n0 * LF;
    float* eT = ws + OFF_ENERGY;
#pragma unroll
    for (int j = 0; j < 16; ++j) {
        int i = tid + j * 256;
        float e = env[base + i];
        float nz = noise[base + i];
        tile[i >> 4][i & 15] = e * (nz * 2.0f - 1.0f);
    }
    __syncthreads();
#pragma unroll
    for (int f = 0; f < 16; ++f) {
        eT[(size_t)(be * 16 + f) * LW + n0 + tid] = tile[tid][f];
    }
}

// ---------------- kernel 2a: per-(be,chunk) partial max of mag^2
__global__ __launch_bounds__(256) void k_maxpart(const float* __restrict__ tf,
                                                 float* __restrict__ ws) {
    __shared__ float red[256];
    int be = blockIdx.x >> 3;
    int chunk = blockIdx.x & 7;
    int tid = threadIdx.x;
    const float* tfb = tf + (size_t)be * 65568;   // 4098*16
    int start = chunk * 4098, end = start + 4098; // 8*4098 = 32784 = 2049*16
    float mx = 0.f;
    for (int i = start + tid; i < end; i += 256) {
        int c = i >> 4, f = i & 15;
        float a = tfb[c * 32 + f];
        float b = tfb[c * 32 + 16 + f];
        mx = fmaxf(mx, a * a + b * b);
    }
    red[tid] = mx;
    __syncthreads();
    for (int s = 128; s > 0; s >>= 1) {
        if (tid < s) red[tid] = fmaxf(red[tid], red[tid + s]);
        __syncthreads();
    }
    if (tid == 0) ws[OFF_MAXP + blockIdx.x] = red[0];
}

// ---------------- kernel 2b: T'[be][f][c] = tfc/2048 (ortho scales folded in)
__global__ __launch_bounds__(256) void k_tfc(const float* __restrict__ tf,
                                             float* __restrict__ ws) {
    int be = blockIdx.x >> 4;
    int f = blockIdx.x & 15;
    const float* tfb = tf + (size_t)be * 65568;
    const float* mp = ws + OFF_MAXP + be * 8;
    float m2 = fmaxf(fmaxf(fmaxf(mp[0], mp[1]), fmaxf(mp[2], mp[3])),
                     fmaxf(fmaxf(mp[4], mp[5]), fmaxf(mp[6], mp[7])));
    float rden = 1.0f / (sqrtf(m2) + 1e-8f);
    float2* Tp = (float2*)(ws + OFF_TP);
    size_t tb = (size_t)(be * 16 + f) * LC;
    const float PIF = 3.14159265358979323846f;
    const float SCL = 1.0f / 2048.0f;
    for (int c = threadIdx.x; c < LC; c += 256) {
        float a = tfb[c * 32 + f];
        float b = tfb[c * 32 + 16 + f];
        float im = tfb[32784 + c * 16 + f];
        float mh = sqrtf(a * a + b * b) * rden;
        float ph = atan2f(im, mh) * PIF;
        float sp, cp;
        sincosf(ph, &sp, &cp);
        Tp[tb + c] = make_float2(mh * cp * SCL, mh * sp * SCL);
    }
}

// ---------------- kernel 3: the sequential 16-frame FFT recurrence + OLA
#define SBD 512
__global__ __launch_bounds__(SBD) void k_scan(float* __restrict__ ws) {
    __shared__ float2 xprev[MM];               // previous frame (4096 reals as float2)
    __shared__ float cr[MM], ci[MM];           // complex work buffer
    __shared__ float t2c[1024], t2s[1024];     // cos/sin(2*pi*j/2048)
    __shared__ float t4c[1025], t4s[1025];     // cos/sin(2*pi*k/4096), k<=1024
    int tid = threadIdx.x;
    int be = blockIdx.x;
    const float2* eT = (const float2*)(ws + OFF_ENERGY);
    const float2* Tp = (const float2*)(ws + OFF_TP);
    float2* atoms = (float2*)(ws + OFF_ATOMS);

    for (int j = tid; j < 1024; j += SBD) {
        float ang = (float)j * (6.28318530717958647692f / 2048.0f);
        t2c[j] = cosf(ang);
        t2s[j] = sinf(ang);
    }
    for (int k = tid; k <= 1024; k += SBD) {
        float ang = (float)k * (6.28318530717958647692f / 4096.0f);
        t4c[k] = cosf(ang);
        t4s[k] = sinf(ang);
    }
    for (int n = tid; n < MM; n += SBD) xprev[n] = make_float2(0.f, 0.f);
    __syncthreads();

    for (int f = 0; f < LF; ++f) {
        // ---- input: z[n] = (x[2n]+e[2n]) + i*(x[2n+1]+e[2n+1])
        size_t ebase = (size_t)(be * 16 + f) * MM;
        for (int n = tid; n < MM; n += SBD) {
            float2 e = eT[ebase + n];
            float2 xp = xprev[n];
            cr[n] = xp.x + e.x;
            ci[n] = xp.y + e.y;
        }
        __syncthreads();
        // ---- forward FFT: in-place DIF (natural in, bit-reversed out), e^{-i}
        for (int t = 0; t < 11; ++t) {
            int h = 1024 >> t;
            for (int i = tid; i < 1024; i += SBD) {
                int q = i & (h - 1);
                int j = ((i >> (10 - t)) << (11 - t)) + q;
                int jb = j + h;
                float ar = cr[j], ai = ci[j];
                float br = cr[jb], bi = ci[jb];
                float dr = ar - br, di = ai - bi;
                int tiw = q << t;
                float c = t2c[tiw], s = t2s[tiw];
                cr[j] = ar + br;
                ci[j] = ai + bi;
                cr[jb] = dr * c + di * s;   // (dr+i di)*(c - i s)
                ci[jb] = di * c - dr * s;
            }
            __syncthreads();
        }
        // ---- fused: rfft-unpack, multiply by T', irfft-repack (bitrev addressing)
        size_t tb = (size_t)(be * 16 + f) * LC;
        for (int k = tid; k <= 1024; k += SBD) {
            int rk = (int)(__brev((unsigned)k) >> 21);
            int rmk = (int)(__brev((unsigned)((MM - k) & (MM - 1))) >> 21);
            float zkr = cr[rk], zki = ci[rk];
            float zmr = cr[rmk], zmi = ci[rmk];
            float xer = 0.5f * (zkr + zmr), xei = 0.5f * (zki - zmi);
            float xor_ = 0.5f * (zki + zmi), xoi = 0.5f * (zmr - zkr);
            float c = t4c[k], s = t4s[k];
            float wXor = xor_ * c + xoi * s;   // Xo * (c - i s)
            float wXoi = xoi * c - xor_ * s;
            float Xkr = xer + wXor, Xki = xei + wXoi;       // X[k]
            float Xmr = xer - wXor, Xmi = wXoi - xei;       // X[2048-k] = conj(Xe - wXo)
            if (k == 0) {
                float2 T0 = Tp[tb + 0];
                float2 TM = Tp[tb + MM];
                float y0 = Xkr * T0.x;   // imag of DC ignored by irfft
                float yn = Xmr * TM.x;   // imag of Nyquist ignored
                cr[0] = 0.5f * (y0 + yn);
                ci[0] = 0.5f * (y0 - yn);
            } else {
                float2 Tk = Tp[tb + k];
                float2 Tm = Tp[tb + (MM - k)];
                float ykr = Xkr * Tk.x - Xki * Tk.y;
                float yki = Xkr * Tk.y + Xki * Tk.x;
                float ymr = Xmr * Tm.x - Xmi * Tm.y;
                float ymi = Xmr * Tm.y + Xmi * Tm.x;
                float er = 0.5f * (ykr + ymr), ei = 0.5f * (yki - ymi);
                float dr = ykr - ymr, di = yki + ymi;
                float or_ = 0.5f * (dr * c - di * s);   // 0.5 * (c + i s) * D
                float oi = 0.5f * (dr * s + di * c);
                cr[rk] = er - oi;          // Z'[k] = E + iO
                ci[rk] = ei + or_;
                cr[rmk] = er + oi;         // Z'[2048-k] = conj(E - iO)
                ci[rmk] = or_ - ei;
            }
        }
        __syncthreads();
        // ---- inverse: in-place DIT (bit-reversed in, natural out), e^{+i}
        for (int t = 0; t < 11; ++t) {
            int h = 1 << t;
            for (int i = tid; i < 1024; i += SBD) {
                int q = i & (h - 1);
                int j = ((i >> t) << (t + 1)) + q;
                int jb = j + h;
                int tiw = q << (10 - t);
                float c = t2c[tiw], s = t2s[tiw];
                float br = cr[jb], bi = ci[jb];
                float tr = br * c - bi * s, tii = br * s + bi * c;
                float ar = cr[j], ai = ci[j];
                cr[j] = ar + tr;
                ci[j] = ai + tii;
                cr[jb] = ar - tr;
                ci[jb] = ai - tii;
            }
            __syncthreads();
        }
        // ---- OLA: chunk f = newframe[0:2048) + prevframe[2048:4096)
        size_t abase = (size_t)be * (NSAMP / 2) + (size_t)f * 1024;
        for (int n = tid; n < 1024; n += SBD) {
            float2 xp = xprev[1024 + n];
            atoms[abase + n] = make_float2(cr[n] + xp.x, ci[n] + xp.y);
        }
        __syncthreads();
        for (int n = tid; n < MM; n += SBD) {
            xprev[n] = make_float2(cr[n], ci[n]);
        }
        __syncthreads();
    }
}

// ---------------- kernel 4: gather-based segment render
__global__ __launch_bounds__(256) void k_segment(const float* __restrict__ ws,
                                                 const int* __restrict__ indices,
                                                 float* __restrict__ out) {
    int gid = blockIdx.x * 256 + threadIdx.x;   // 65536 threads, one float4 each
    int b = gid >> 13;                          // 8192 float4 per batch
    int t = (gid & 8191) << 2;
    const float* atoms = ws + OFF_ATOMS;
    float4 acc = make_float4(0.f, 0.f, 0.f, 0.f);
#pragma unroll
    for (int e = 0; e < NEV; ++e) {
        int te = indices[b * NEV + e] * 256;
        if (t >= te) {
            const float4 v = *(const float4*)(atoms + (size_t)(b * NEV + e) * NSAMP + (t - te));
            acc.x += v.x;
            acc.y += v.y;
            acc.z += v.z;
            acc.w += v.w;
        }
    }
    ((float4*)out)[gid] = acc;
}

extern "C" void kernel_launch(void* const* d_in, const int* in_sizes, int n_in,
                              void* d_out, int out_size, void* d_ws, size_t ws_size,
                              hipStream_t stream) {
    const float* env = (const float*)d_in[0];
    const float* tf = (const float*)d_in[1];
    const float* noise = (const float*)d_in[2];
    const int* indices = (const int*)d_in[3];
    float* ws = (float*)d_ws;
    float* out = (float*)d_out;

    k_energy<<<dim3(2048), dim3(256), 0, stream>>>(env, noise, ws);
    k_maxpart<<<dim3(1024), dim3(256), 0, stream>>>(tf, ws);
    k_tfc<<<dim3(2048), dim3(256), 0, stream>>>(tf, ws);
    k_scan<<<dim3(128), dim3(SBD), 0, stream>>>(ws);
    k_segment<<<dim3(256), dim3(256), 0, stream>>>(ws, indices, out);
}

// Round 2
// 111.068 us; speedup vs baseline: 3.2027x; 3.2027x over previous
//
#include <hip/hip_runtime.h>
#include <math.h>

#define BE 128
#define LW 4096
#define LF 16
#define LC 2049
#define NSAMP 32768
#define TWO_PI 6.283185307179586f

// workspace layout (floats)
#define OFF_ET   0ull          // energy transposed [be][f][4096]; later reused for frames
#define OFF_E    8388608ull    // spectra E/Y [be][f][2049] float2
#define OFF_MAXP 16781312ull   // 1024 partial maxima

__device__ __forceinline__ int swz(int n) { return n ^ ((n >> 5) & 31); }

// position of natural index k after DIF with radices [2,4,4,4,4,4]
__device__ __forceinline__ int permf(int k) {
    return ((k & 1) << 10) | (((k >> 1) & 3) << 8) | (((k >> 3) & 3) << 6)
         | (((k >> 5) & 3) << 4) | (((k >> 7) & 3) << 2) | ((k >> 9) & 3);
}

__device__ __forceinline__ void r4_fwd(float* cr, float* ci, int j, int h, float ang) {
    int p0 = swz(j), p1 = swz(j + h), p2 = swz(j + 2 * h), p3 = swz(j + 3 * h);
    float ar = cr[p0], ai = ci[p0];
    float br = cr[p1], bi = ci[p1];
    float crr = cr[p2], cri = ci[p2];
    float drr = cr[p3], dri = ci[p3];
    float u0r = ar + crr, u0i = ai + cri;
    float u1r = ar - crr, u1i = ai - cri;
    float u2r = br + drr, u2i = bi + dri;
    float u3r = br - drr, u3i = bi - dri;
    float s1, c1; __sincosf(ang, &s1, &c1);
    float c2 = c1 * c1 - s1 * s1, s2 = 2.f * c1 * s1;
    float c3 = c1 * c2 - s1 * s2, s3 = s1 * c2 + c1 * s2;
    cr[p0] = u0r + u2r; ci[p0] = u0i + u2i;
    float z1r = u1r + u3i, z1i = u1i - u3r;            // u1 - i*u3
    cr[p1] = z1r * c1 + z1i * s1; ci[p1] = z1i * c1 - z1r * s1;
    float z2r = u0r - u2r, z2i = u0i - u2i;
    cr[p2] = z2r * c2 + z2i * s2; ci[p2] = z2i * c2 - z2r * s2;
    float z3r = u1r - u3i, z3i = u1i + u3r;            // u1 + i*u3
    cr[p3] = z3r * c3 + z3i * s3; ci[p3] = z3i * c3 - z3r * s3;
}

__device__ __forceinline__ void r4_inv(float* cr, float* ci, int j, int h, float ang) {
    int p0 = swz(j), p1 = swz(j + h), p2 = swz(j + 2 * h), p3 = swz(j + 3 * h);
    float z0r = cr[p0], z0i = ci[p0];
    float z1r = cr[p1], z1i = ci[p1];
    float z2r = cr[p2], z2i = ci[p2];
    float z3r = cr[p3], z3i = ci[p3];
    float s1, c1; __sincosf(ang, &s1, &c1);
    float c2 = c1 * c1 - s1 * s1, s2 = 2.f * c1 * s1;
    float c3 = c1 * c2 - s1 * s2, s3 = s1 * c2 + c1 * s2;
    float t1r = z1r * c1 - z1i * s1, t1i = z1i * c1 + z1r * s1;
    float t2r = z2r * c2 - z2i * s2, t2i = z2i * c2 + z2r * s2;
    float t3r = z3r * c3 - z3i * s3, t3i = z3i * c3 + z3r * s3;
    float u0r = z0r + t2r, u0i = z0i + t2i;
    float u1r = z0r - t2r, u1i = z0i - t2i;
    float u2r = t1r + t3r, u2i = t1i + t3i;
    float u3r = t1r - t3r, u3i = t1i - t3i;
    cr[p0] = u0r + u2r; ci[p0] = u0i + u2i;
    cr[p1] = u1r - u3i; ci[p1] = u1i + u3r;            // u1 + i*u3
    cr[p2] = u0r - u2r; ci[p2] = u0i - u2i;
    cr[p3] = u1r + u3i; ci[p3] = u1i - u3r;            // u1 - i*u3
}

// ---- energy = env*(2*noise-1), transposed to [be][f][n]
__global__ __launch_bounds__(256) void k_energy(const float* __restrict__ env,
                                                const float* __restrict__ noise,
                                                float* __restrict__ ws) {
    __shared__ float tile[256][17];
    int be = blockIdx.x >> 4;
    int n0 = (blockIdx.x & 15) << 8;
    int tid = threadIdx.x;
    size_t base = (size_t)be * (LW * LF) + (size_t)n0 * LF;
    float* eT = ws + OFF_ET;
#pragma unroll
    for (int j = 0; j < 16; ++j) {
        int i = tid + j * 256;
        float e = env[base + i];
        float nz = noise[base + i];
        tile[i >> 4][i & 15] = e * (nz * 2.0f - 1.0f);
    }
    __syncthreads();
#pragma unroll
    for (int f = 0; f < 16; ++f)
        eT[(size_t)(be * 16 + f) * LW + n0 + tid] = tile[tid][f];
}

// ---- per-(be,chunk) partial max of mag^2
__global__ __launch_bounds__(256) void k_maxpart(const float* __restrict__ tf,
                                                 float* __restrict__ ws) {
    __shared__ float red[256];
    int be = blockIdx.x >> 3;
    int chunk = blockIdx.x & 7;
    int tid = threadIdx.x;
    const float* tfb = tf + (size_t)be * 65568;
    int start = chunk * 4098, end = start + 4098;
    float mx = 0.f;
    for (int i = start + tid; i < end; i += 256) {
        int c = i >> 4, f = i & 15;
        float a = tfb[c * 32 + f];
        float b = tfb[c * 32 + 16 + f];
        mx = fmaxf(mx, a * a + b * b);
    }
    red[tid] = mx;
    __syncthreads();
    for (int s = 128; s > 0; s >>= 1) {
        if (tid < s) red[tid] = fmaxf(red[tid], red[tid + s]);
        __syncthreads();
    }
    if (tid == 0) ws[OFF_MAXP + blockIdx.x] = red[0];
}

// ---- forward FFT of energy frames: E[be][f][k] (unnormalized rfft)
__global__ __launch_bounds__(512) void k_fft_fwd(float* __restrict__ ws) {
    __shared__ float cr[2048], ci[2048];
    int tid = threadIdx.x;
    int be = blockIdx.x >> 4, f = blockIdx.x & 15;
    const float4* src = (const float4*)(ws + OFF_ET) + (size_t)(be * 16 + f) * 1024;
#pragma unroll
    for (int it = 0; it < 2; ++it) {
        int idx = tid + it * 512;
        float4 v = src[idx];
        int n0 = idx * 2;
        cr[swz(n0)] = v.x;     ci[swz(n0)] = v.y;
        cr[swz(n0 + 1)] = v.z; ci[swz(n0 + 1)] = v.w;
    }
    __syncthreads();
#pragma unroll
    for (int it = 0; it < 2; ++it) {                   // radix-2 DIF, h=1024
        int i = tid + it * 512;
        int sj = swz(i), sjb = swz(i + 1024);
        float ar = cr[sj], ai = ci[sj], br = cr[sjb], bi = ci[sjb];
        float dr = ar - br, di = ai - bi;
        float s, c; __sincosf((float)i * (TWO_PI / 2048.0f), &s, &c);
        cr[sj] = ar + br; ci[sj] = ai + bi;
        cr[sjb] = dr * c + di * s; ci[sjb] = di * c - dr * s;
    }
    __syncthreads();
    r4_fwd(cr, ci, (tid >> 8) * 1024 + (tid & 255), 256, (float)(tid & 255) * (TWO_PI / 1024.0f)); __syncthreads();
    r4_fwd(cr, ci, (tid >> 6) * 256 + (tid & 63), 64, (float)(tid & 63) * (TWO_PI / 256.0f)); __syncthreads();
    r4_fwd(cr, ci, (tid & 31) * 64 + (tid >> 5), 16, (float)(tid >> 5) * (TWO_PI / 64.0f)); __syncthreads();
    r4_fwd(cr, ci, (tid & 127) * 16 + (tid >> 7), 4, (float)(tid >> 7) * (TWO_PI / 16.0f)); __syncthreads();
    r4_fwd(cr, ci, tid * 4, 1, 0.0f); __syncthreads();
    float2* Eg = (float2*)(ws + OFF_E) + (size_t)(be * 16 + f) * 2049;
    for (int k = tid; k <= 1024; k += 512) {
        int pk = swz(permf(k));
        int pm = swz(permf((2048 - k) & 2047));
        float zkr = cr[pk], zki = ci[pk], zmr = cr[pm], zmi = ci[pm];
        float xer = 0.5f * (zkr + zmr), xei = 0.5f * (zki - zmi);
        float xor_ = 0.5f * (zki + zmi), xoi = 0.5f * (zmr - zkr);
        float s4, c4; __sincosf((float)k * (TWO_PI / 4096.0f), &s4, &c4);
        float wr = xor_ * c4 + xoi * s4;
        float wi = xoi * c4 - xor_ * s4;
        Eg[k] = make_float2(xer + wr, xei + wi);
        Eg[2048 - k] = make_float2(xer - wr, wi - xei);
    }
}

// ---- per-bin recurrence: S_f = (zeroDCNyqImag(S_{f-1}) + E_f) * T_f, in place
__global__ __launch_bounds__(256) void k_recur(const float* __restrict__ tf,
                                               float* __restrict__ ws) {
    int k = blockIdx.x * 256 + threadIdx.x;
    int be = blockIdx.y;
    if (k > 2048) return;
    const float* mp = ws + OFF_MAXP + be * 8;
    float m2 = fmaxf(fmaxf(fmaxf(mp[0], mp[1]), fmaxf(mp[2], mp[3])),
                     fmaxf(fmaxf(mp[4], mp[5]), fmaxf(mp[6], mp[7])));
    float rden = 1.0f / (sqrtf(m2) + 1e-8f);
    const float* tfb = tf + (size_t)be * 65568;
    float2* Eg = (float2*)(ws + OFF_E) + (size_t)be * 16 * 2049 + k;
    bool edge = (k == 0) || (k == 2048);
    float sr = 0.f, si = 0.f;
#pragma unroll
    for (int f = 0; f < 16; ++f) {
        float a = tfb[k * 32 + f];
        float b = tfb[k * 32 + 16 + f];
        float im = tfb[32784 + k * 16 + f];
        float mh = sqrtf(a * a + b * b) * rden;
        float ph = atan2f(im, mh) * 3.14159265358979f;
        float sp, cp; __sincosf(ph, &sp, &cp);
        float Tr = mh * cp, Ti = mh * sp;
        if (edge) si = 0.f;
        float2 e = Eg[(size_t)f * 2049];
        sr += e.x; si += e.y;
        float nr = sr * Tr - si * Ti;
        float ni = sr * Ti + si * Tr;
        sr = nr; si = ni;
        Eg[(size_t)f * 2049] = make_float2(sr, si);
    }
}

// ---- inverse FFT: Y[be][f] -> frame samples [be][f][4096] (reuses OFF_ET)
__global__ __launch_bounds__(512) void k_fft_inv(float* __restrict__ ws) {
    __shared__ float cr[2048], ci[2048];
    int tid = threadIdx.x;
    int be = blockIdx.x >> 4, f = blockIdx.x & 15;
    const float2* Yg = (const float2*)(ws + OFF_E) + (size_t)(be * 16 + f) * 2049;
    const float SCL = 1.0f / 2048.0f;
    for (int k = tid; k <= 1024; k += 512) {
        float2 Yk = Yg[k];
        float2 Ym = Yg[2048 - k];
        if (k == 0) {
            float y0 = Yk.x * SCL, yn = Ym.x * SCL;   // DC/Nyq: imag ignored
            cr[swz(0)] = 0.5f * (y0 + yn);
            ci[swz(0)] = 0.5f * (y0 - yn);
        } else {
            float ykr = Yk.x * SCL, yki = Yk.y * SCL;
            float ymr = Ym.x * SCL, ymi = Ym.y * SCL;
            float er = 0.5f * (ykr + ymr), ei = 0.5f * (yki - ymi);
            float dr = ykr - ymr, di = yki + ymi;
            float s4, c4; __sincosf((float)k * (TWO_PI / 4096.0f), &s4, &c4);
            float orr = 0.5f * (dr * c4 - di * s4);
            float oi = 0.5f * (dr * s4 + di * c4);
            int pk = swz(permf(k)), pm = swz(permf(2048 - k));
            cr[pk] = er - oi; ci[pk] = ei + orr;
            cr[pm] = er + oi; ci[pm] = orr - ei;
        }
    }
    __syncthreads();
    r4_inv(cr, ci, tid * 4, 1, 0.0f); __syncthreads();
    r4_inv(cr, ci, (tid & 127) * 16 + (tid >> 7), 4, (float)(tid >> 7) * (TWO_PI / 16.0f)); __syncthreads();
    r4_inv(cr, ci, (tid & 31) * 64 + (tid >> 5), 16, (float)(tid >> 5) * (TWO_PI / 64.0f)); __syncthreads();
    r4_inv(cr, ci, (tid >> 6) * 256 + (tid & 63), 64, (float)(tid & 63) * (TWO_PI / 256.0f)); __syncthreads();
    r4_inv(cr, ci, (tid >> 8) * 1024 + (tid & 255), 256, (float)(tid & 255) * (TWO_PI / 1024.0f)); __syncthreads();
#pragma unroll
    for (int it = 0; it < 2; ++it) {                   // radix-2 DIT, h=1024
        int i = tid + it * 512;
        int sj = swz(i), sjb = swz(i + 1024);
        float s, c; __sincosf((float)i * (TWO_PI / 2048.0f), &s, &c);
        float br = cr[sjb], bi = ci[sjb];
        float tr = br * c - bi * s, ti2 = br * s + bi * c;
        float ar = cr[sj], ai = ci[sj];
        cr[sj] = ar + tr;  ci[sj] = ai + ti2;
        cr[sjb] = ar - tr; ci[sjb] = ai - ti2;
    }
    __syncthreads();
    float2* Fg = (float2*)(ws + OFF_ET) + (size_t)(be * 16 + f) * 2048;
#pragma unroll
    for (int it = 0; it < 4; ++it) {
        int m = tid + it * 512;
        Fg[m] = make_float2(cr[swz(m)], ci[swz(m)]);
    }
}

// ---- gather + fused overlap-add
__global__ __launch_bounds__(256) void k_segment(const float* __restrict__ ws,
                                                 const int* __restrict__ indices,
                                                 float* __restrict__ out) {
    int gid = blockIdx.x * 256 + threadIdx.x;
    int b = gid >> 13;
    int t = (gid & 8191) << 2;
    const float* F = ws + OFF_ET;
    float4 acc = make_float4(0.f, 0.f, 0.f, 0.f);
#pragma unroll
    for (int e = 0; e < 16; ++e) {
        int te = indices[b * 16 + e] * 256;
        if (t >= te) {
            int d = t - te;
            int j = d >> 11, r = d & 2047;
            size_t base = (size_t)(b * 16 + e) * 65536;
            float4 v = *(const float4*)(F + base + j * 4096 + r);
            acc.x += v.x; acc.y += v.y; acc.z += v.z; acc.w += v.w;
            if (j >= 1) {
                float4 w = *(const float4*)(F + base + (j - 1) * 4096 + 2048 + r);
                acc.x += w.x; acc.y += w.y; acc.z += w.z; acc.w += w.w;
            }
        }
    }
    ((float4*)out)[gid] = acc;
}

extern "C" void kernel_launch(void* const* d_in, const int* in_sizes, int n_in,
                              void* d_out, int out_size, void* d_ws, size_t ws_size,
                              hipStream_t stream) {
    const float* env = (const float*)d_in[0];
    const float* tf = (const float*)d_in[1];
    const float* noise = (const float*)d_in[2];
    const int* indices = (const int*)d_in[3];
    float* ws = (float*)d_ws;
    float* out = (float*)d_out;

    k_energy<<<dim3(2048), dim3(256), 0, stream>>>(env, noise, ws);
    k_maxpart<<<dim3(1024), dim3(256), 0, stream>>>(tf, ws);
    k_fft_fwd<<<dim3(2048), dim3(512), 0, stream>>>(ws);
    k_recur<<<dim3(9, 128), dim3(256), 0, stream>>>(tf, ws);
    k_fft_inv<<<dim3(2048), dim3(512), 0, stream>>>(ws);
    k_segment<<<dim3(256), dim3(256), 0, stream>>>(ws, indices, out);
}

// Round 3
// 91.662 us; speedup vs baseline: 3.8807x; 1.2117x over previous
//
#include <hip/hip_runtime.h>
#include <math.h>

#define TWO_PI 6.283185307179586f

// workspace layout (floats)
#define OFF_ET   0ull          // energy transposed [be][f][4096]; later reused for frames
#define OFF_E    8388608ull    // spectra E/Y [be][f][2049] float2
#define OFF_MAXP 16781312ull   // 1024 partial maxima

__device__ __forceinline__ int swz(int n) { return n ^ ((n >> 5) & 31); }

// position of natural index k after DIF with radices [2,4,4,4,4,4]
__device__ __forceinline__ int permf(int k) {
    return ((k & 1) << 10) | (((k >> 1) & 3) << 8) | (((k >> 3) & 3) << 6)
         | (((k >> 5) & 3) << 4) | (((k >> 7) & 3) << 2) | ((k >> 9) & 3);
}

__device__ __forceinline__ void r4_fwd(float* cr, float* ci, int j, int h, float ang) {
    int p0 = swz(j), p1 = swz(j + h), p2 = swz(j + 2 * h), p3 = swz(j + 3 * h);
    float ar = cr[p0], ai = ci[p0];
    float br = cr[p1], bi = ci[p1];
    float crr = cr[p2], cri = ci[p2];
    float drr = cr[p3], dri = ci[p3];
    float u0r = ar + crr, u0i = ai + cri;
    float u1r = ar - crr, u1i = ai - cri;
    float u2r = br + drr, u2i = bi + dri;
    float u3r = br - drr, u3i = bi - dri;
    float s1, c1; __sincosf(ang, &s1, &c1);
    float c2 = c1 * c1 - s1 * s1, s2 = 2.f * c1 * s1;
    float c3 = c1 * c2 - s1 * s2, s3 = s1 * c2 + c1 * s2;
    cr[p0] = u0r + u2r; ci[p0] = u0i + u2i;
    float z1r = u1r + u3i, z1i = u1i - u3r;            // u1 - i*u3
    cr[p1] = z1r * c1 + z1i * s1; ci[p1] = z1i * c1 - z1r * s1;
    float z2r = u0r - u2r, z2i = u0i - u2i;
    cr[p2] = z2r * c2 + z2i * s2; ci[p2] = z2i * c2 - z2r * s2;
    float z3r = u1r - u3i, z3i = u1i + u3r;            // u1 + i*u3
    cr[p3] = z3r * c3 + z3i * s3; ci[p3] = z3i * c3 - z3r * s3;
}

__device__ __forceinline__ void r4_inv(float* cr, float* ci, int j, int h, float ang) {
    int p0 = swz(j), p1 = swz(j + h), p2 = swz(j + 2 * h), p3 = swz(j + 3 * h);
    float z0r = cr[p0], z0i = ci[p0];
    float z1r = cr[p1], z1i = ci[p1];
    float z2r = cr[p2], z2i = ci[p2];
    float z3r = cr[p3], z3i = ci[p3];
    float s1, c1; __sincosf(ang, &s1, &c1);
    float c2 = c1 * c1 - s1 * s1, s2 = 2.f * c1 * s1;
    float c3 = c1 * c2 - s1 * s2, s3 = s1 * c2 + c1 * s2;
    float t1r = z1r * c1 - z1i * s1, t1i = z1i * c1 + z1r * s1;
    float t2r = z2r * c2 - z2i * s2, t2i = z2i * c2 + z2r * s2;
    float t3r = z3r * c3 - z3i * s3, t3i = z3i * c3 + z3r * s3;
    float u0r = z0r + t2r, u0i = z0i + t2i;
    float u1r = z0r - t2r, u1i = z0i - t2i;
    float u2r = t1r + t3r, u2i = t1i + t3i;
    float u3r = t1r - t3r, u3i = t1i - t3i;
    cr[p0] = u0r + u2r; ci[p0] = u0i + u2i;
    cr[p1] = u1r - u3i; ci[p1] = u1i + u3r;            // u1 + i*u3
    cr[p2] = u0r - u2r; ci[p2] = u0i - u2i;
    cr[p3] = u1r + u3i; ci[p3] = u1i - u3r;            // u1 - i*u3
}

// ---- merged: energy transpose (blocks 0..2047) + tf max reduction (blocks 2048..3071)
__global__ __launch_bounds__(256) void k_prep(const float* __restrict__ env,
                                              const float* __restrict__ noise,
                                              const float* __restrict__ tf,
                                              float* __restrict__ ws) {
    __shared__ float tile[256][17];
    int tid = threadIdx.x;
    if (blockIdx.x < 2048) {
        int be = blockIdx.x >> 4;
        int n0 = (blockIdx.x & 15) << 8;
        size_t base = (size_t)be * 65536 + (size_t)n0 * 16;
        float* eT = ws + OFF_ET;
#pragma unroll
        for (int j = 0; j < 16; ++j) {
            int i = tid + j * 256;
            float e = env[base + i];
            float nz = noise[base + i];
            tile[i >> 4][i & 15] = e * (nz * 2.0f - 1.0f);
        }
        __syncthreads();
#pragma unroll
        for (int f = 0; f < 16; ++f)
            eT[(size_t)(be * 16 + f) * 4096 + n0 + tid] = tile[tid][f];
    } else {
        int bb = blockIdx.x - 2048;
        int be = bb >> 3;
        int chunk = bb & 7;
        const float* tfb = tf + (size_t)be * 65568;
        float* red = &tile[0][0];
        int start = chunk * 4098, end = start + 4098;
        float mx = 0.f;
        for (int i = start + tid; i < end; i += 256) {
            int c = i >> 4, f = i & 15;
            float a = tfb[c * 32 + f];
            float b = tfb[c * 32 + 16 + f];
            mx = fmaxf(mx, a * a + b * b);
        }
        red[tid] = mx;
        __syncthreads();
        for (int s = 128; s > 0; s >>= 1) {
            if (tid < s) red[tid] = fmaxf(red[tid], red[tid + s]);
            __syncthreads();
        }
        if (tid == 0) ws[OFF_MAXP + bb] = red[0];
    }
}

// ---- forward FFT of energy frames: E[be][f][k] (unnormalized rfft)
__global__ __launch_bounds__(512) void k_fft_fwd(float* __restrict__ ws) {
    __shared__ float cr[2048], ci[2048];
    int tid = threadIdx.x;
    int be = blockIdx.x >> 4, f = blockIdx.x & 15;
    const float4* src = (const float4*)(ws + OFF_ET) + (size_t)(be * 16 + f) * 1024;
#pragma unroll
    for (int it = 0; it < 2; ++it) {
        int idx = tid + it * 512;
        float4 v = src[idx];
        int n0 = idx * 2;
        cr[swz(n0)] = v.x;     ci[swz(n0)] = v.y;
        cr[swz(n0 + 1)] = v.z; ci[swz(n0 + 1)] = v.w;
    }
    __syncthreads();
#pragma unroll
    for (int it = 0; it < 2; ++it) {                   // radix-2 DIF, h=1024
        int i = tid + it * 512;
        int sj = swz(i), sjb = swz(i + 1024);
        float ar = cr[sj], ai = ci[sj], br = cr[sjb], bi = ci[sjb];
        float dr = ar - br, di = ai - bi;
        float s, c; __sincosf((float)i * (TWO_PI / 2048.0f), &s, &c);
        cr[sj] = ar + br; ci[sj] = ai + bi;
        cr[sjb] = dr * c + di * s; ci[sjb] = di * c - dr * s;
    }
    __syncthreads();
    r4_fwd(cr, ci, (tid >> 8) * 1024 + (tid & 255), 256, (float)(tid & 255) * (TWO_PI / 1024.0f)); __syncthreads();
    r4_fwd(cr, ci, (tid >> 6) * 256 + (tid & 63), 64, (float)(tid & 63) * (TWO_PI / 256.0f)); __syncthreads();
    r4_fwd(cr, ci, (tid & 31) * 64 + (tid >> 5), 16, (float)(tid >> 5) * (TWO_PI / 64.0f)); __syncthreads();
    r4_fwd(cr, ci, (tid & 127) * 16 + (tid >> 7), 4, (float)(tid >> 7) * (TWO_PI / 16.0f)); __syncthreads();
    r4_fwd(cr, ci, tid * 4, 1, 0.0f); __syncthreads();
    float2* Eg = (float2*)(ws + OFF_E) + (size_t)(be * 16 + f) * 2049;
    for (int k = tid; k <= 1024; k += 512) {
        int pk = swz(permf(k));
        int pm = swz(permf((2048 - k) & 2047));
        float zkr = cr[pk], zki = ci[pk], zmr = cr[pm], zmi = ci[pm];
        float xer = 0.5f * (zkr + zmr), xei = 0.5f * (zki - zmi);
        float xor_ = 0.5f * (zki + zmi), xoi = 0.5f * (zmr - zkr);
        float s4, c4; __sincosf((float)k * (TWO_PI / 4096.0f), &s4, &c4);
        float wr = xor_ * c4 + xoi * s4;
        float wi = xoi * c4 - xor_ * s4;
        Eg[k] = make_float2(xer + wr, xei + wi);
        Eg[2048 - k] = make_float2(xer - wr, wi - xei);
    }
}

// ---- per-bin recurrence, LDS-staged tf (coalesced), E prefetched to registers
__global__ __launch_bounds__(256) void k_recur(const float* __restrict__ tf,
                                               float* __restrict__ ws) {
    __shared__ float sm2[256 * 17];   // mag^2 [k][f], pad 17
    __shared__ float sim[256 * 17];   // imag  [k][f], pad 17
    int tid = threadIdx.x;
    int be = blockIdx.y;
    int k0 = blockIdx.x << 8;
    int nk = 2049 - k0; if (nk > 256) nk = 256;
    const float* tfb = tf + (size_t)be * 65568;
    const float4* ab4 = (const float4*)tfb;           // a,b region, group k = f4 [k*8, k*8+8)
    const float4* im4 = (const float4*)(tfb + 32784); // imag region, k = f4 [k*4, k*4+4)

    // stage: m2 = a^2+b^2 and imag, coalesced float4 loads
    for (int u = tid; u < nk * 4; u += 256) {
        int g = u >> 2, e = u & 3;
        float4 A = ab4[(k0 + g) * 8 + e];
        float4 Bv = ab4[(k0 + g) * 8 + e + 4];
        float4 I = im4[(k0 + g) * 4 + e];
        int o = g * 17 + e * 4;
        sm2[o + 0] = A.x * A.x + Bv.x * Bv.x;
        sm2[o + 1] = A.y * A.y + Bv.y * Bv.y;
        sm2[o + 2] = A.z * A.z + Bv.z * Bv.z;
        sm2[o + 3] = A.w * A.w + Bv.w * Bv.w;
        sim[o + 0] = I.x; sim[o + 1] = I.y; sim[o + 2] = I.z; sim[o + 3] = I.w;
    }
    __syncthreads();

    if (tid >= nk) return;
    int kg = k0 + tid;
    const float* mp = ws + OFF_MAXP + be * 8;
    float m2x = fmaxf(fmaxf(fmaxf(mp[0], mp[1]), fmaxf(mp[2], mp[3])),
                      fmaxf(fmaxf(mp[4], mp[5]), fmaxf(mp[6], mp[7])));
    float rden = 1.0f / (sqrtf(m2x) + 1e-8f);
    float2* Eg = (float2*)(ws + OFF_E) + (size_t)be * 16 * 2049 + kg;
    float2 ev[16];
#pragma unroll
    for (int f = 0; f < 16; ++f) ev[f] = Eg[(size_t)f * 2049];
    float ym = (kg == 0 || kg == 2048) ? 0.0f : 1.0f;
    float sr = 0.f, si = 0.f;
#pragma unroll
    for (int f = 0; f < 16; ++f) {
        float mh = sqrtf(sm2[tid * 17 + f]) * rden;
        float ph = atan2f(sim[tid * 17 + f], mh) * 3.14159265358979f;
        float sp, cp; __sincosf(ph, &sp, &cp);
        float Tr = mh * cp, Ti = mh * sp;
        si *= ym;
        sr += ev[f].x; si += ev[f].y;
        float nr = sr * Tr - si * Ti;
        si = sr * Ti + si * Tr;
        sr = nr;
        Eg[(size_t)f * 2049] = make_float2(sr, si);
    }
}

// ---- inverse FFT: Y[be][f] -> frame samples [be][f][4096] (reuses OFF_ET)
__global__ __launch_bounds__(512) void k_fft_inv(float* __restrict__ ws) {
    __shared__ float cr[2048], ci[2048];
    int tid = threadIdx.x;
    int be = blockIdx.x >> 4, f = blockIdx.x & 15;
    const float2* Yg = (const float2*)(ws + OFF_E) + (size_t)(be * 16 + f) * 2049;
    const float SCL = 1.0f / 2048.0f;
    for (int k = tid; k <= 1024; k += 512) {
        float2 Yk = Yg[k];
        float2 Ym = Yg[2048 - k];
        if (k == 0) {
            float y0 = Yk.x * SCL, yn = Ym.x * SCL;   // DC/Nyq: imag ignored
            cr[swz(0)] = 0.5f * (y0 + yn);
            ci[swz(0)] = 0.5f * (y0 - yn);
        } else {
            float ykr = Yk.x * SCL, yki = Yk.y * SCL;
            float ymr = Ym.x * SCL, ymi = Ym.y * SCL;
            float er = 0.5f * (ykr + ymr), ei = 0.5f * (yki - ymi);
            float dr = ykr - ymr, di = yki + ymi;
            float s4, c4; __sincosf((float)k * (TWO_PI / 4096.0f), &s4, &c4);
            float orr = 0.5f * (dr * c4 - di * s4);
            float oi = 0.5f * (dr * s4 + di * c4);
            int pk = swz(permf(k)), pm = swz(permf(2048 - k));
            cr[pk] = er - oi; ci[pk] = ei + orr;
            cr[pm] = er + oi; ci[pm] = orr - ei;
        }
    }
    __syncthreads();
    r4_inv(cr, ci, tid * 4, 1, 0.0f); __syncthreads();
    r4_inv(cr, ci, (tid & 127) * 16 + (tid >> 7), 4, (float)(tid >> 7) * (TWO_PI / 16.0f)); __syncthreads();
    r4_inv(cr, ci, (tid & 31) * 64 + (tid >> 5), 16, (float)(tid >> 5) * (TWO_PI / 64.0f)); __syncthreads();
    r4_inv(cr, ci, (tid >> 6) * 256 + (tid & 63), 64, (float)(tid & 63) * (TWO_PI / 256.0f)); __syncthreads();
    r4_inv(cr, ci, (tid >> 8) * 1024 + (tid & 255), 256, (float)(tid & 255) * (TWO_PI / 1024.0f)); __syncthreads();
#pragma unroll
    for (int it = 0; it < 2; ++it) {                   // radix-2 DIT, h=1024
        int i = tid + it * 512;
        int sj = swz(i), sjb = swz(i + 1024);
        float s, c; __sincosf((float)i * (TWO_PI / 2048.0f), &s, &c);
        float br = cr[sjb], bi = ci[sjb];
        float tr = br * c - bi * s, ti2 = br * s + bi * c;
        float ar = cr[sj], ai = ci[sj];
        cr[sj] = ar + tr;  ci[sj] = ai + ti2;
        cr[sjb] = ar - tr; ci[sjb] = ai - ti2;
    }
    __syncthreads();
    float2* Fg = (float2*)(ws + OFF_ET) + (size_t)(be * 16 + f) * 2048;
#pragma unroll
    for (int it = 0; it < 4; ++it) {
        int m = tid + it * 512;
        Fg[m] = make_float2(cr[swz(m)], ci[swz(m)]);
    }
}

// ---- gather + fused overlap-add
__global__ __launch_bounds__(256) void k_segment(const float* __restrict__ ws,
                                                 const int* __restrict__ indices,
                                                 float* __restrict__ out) {
    int gid = blockIdx.x * 256 + threadIdx.x;
    int b = gid >> 13;
    int t = (gid & 8191) << 2;
    const float* F = ws + OFF_ET;
    float4 acc = make_float4(0.f, 0.f, 0.f, 0.f);
#pragma unroll
    for (int e = 0; e < 16; ++e) {
        int te = indices[b * 16 + e] * 256;
        if (t >= te) {
            int d = t - te;
            int j = d >> 11, r = d & 2047;
            size_t base = (size_t)(b * 16 + e) * 65536;
            float4 v = *(const float4*)(F + base + j * 4096 + r);
            acc.x += v.x; acc.y += v.y; acc.z += v.z; acc.w += v.w;
            if (j >= 1) {
                float4 w = *(const float4*)(F + base + (j - 1) * 4096 + 2048 + r);
                acc.x += w.x; acc.y += w.y; acc.z += w.z; acc.w += w.w;
            }
        }
    }
    ((float4*)out)[gid] = acc;
}

extern "C" void kernel_launch(void* const* d_in, const int* in_sizes, int n_in,
                              void* d_out, int out_size, void* d_ws, size_t ws_size,
                              hipStream_t stream) {
    const float* env = (const float*)d_in[0];
    const float* tf = (const float*)d_in[1];
    const float* noise = (const float*)d_in[2];
    const int* indices = (const int*)d_in[3];
    float* ws = (float*)d_ws;
    float* out = (float*)d_out;

    k_prep<<<dim3(3072), dim3(256), 0, stream>>>(env, noise, tf, ws);
    k_fft_fwd<<<dim3(2048), dim3(512), 0, stream>>>(ws);
    k_recur<<<dim3(9, 128), dim3(256), 0, stream>>>(tf, ws);
    k_fft_inv<<<dim3(2048), dim3(512), 0, stream>>>(ws);
    k_segment<<<dim3(256), dim3(256), 0, stream>>>(ws, indices, out);
}